// Round 17
// baseline (28.279 us; speedup 1.0000x reference)
//
#include <hip/hip_runtime.h>

// SelfAttention: x[4,4096,64] f32; Wq,Wk[64,16]; Wv[64,64]; out[4,4096,64] f32.
// R17 = R16 + two-tile interleaved attn inner loop (T15 double-pipeline).
//   Budget (R14-calibrated): fixed ~8-9us, gap ~2.5, proj ~2, attn ~10.4.
//   attn is latency-bound at the 128-reg occupancy ceiling (64V+64A,
//   4 waves/SIMD); per-tile MFMA<->VALU ping-pong (~200cy dead) is exposed.
//   Pairing tiles (t, t+16) with independent s/P/K/V state but shared O
//   accumulators lets tile B's MFMAs cover tile A's exp2/cvt VALU and
//   vice versa.
// proj (R16): 1024-thr staging, waves 0-5 run the 6 MFMA chains; q pre-scaled
//   1/sqrt(16)*log2e; V stored in MFMA fragment order.
// attn: no-max exp2 flash (scores in log2 domain), pair-balanced blocks
//   (129 32-key tiles), osum = P*ones MFMA denominator, 16-way sum merge.

#define TSEQ 4096
#define NBATCH 4

typedef __attribute__((ext_vector_type(4)))  float fvec4;
typedef __attribute__((ext_vector_type(16))) float f32x16;
typedef __attribute__((ext_vector_type(4)))  short s16x4;
typedef __attribute__((ext_vector_type(8)))  short s16x8;

union I4S8 { int i[4]; s16x8 v; };

static __device__ __forceinline__ unsigned short f2bf(float f) {
    unsigned u = __float_as_uint(f);
    u += 0x7FFFu + ((u >> 16) & 1u);   // RNE
    return (unsigned short)(u >> 16);
}

static __device__ __forceinline__ int cvt_pk_bf16(float lo, float hi) {
    int r;
    asm("v_cvt_pk_bf16_f32 %0, %1, %2" : "=v"(r) : "v"(lo), "v"(hi));
    return r;
}

static __device__ __forceinline__ s16x8 cat4(s16x4 a, s16x4 b) {
    return __builtin_shufflevector(a, b, 0, 1, 2, 3, 4, 5, 6, 7);
}

// ---------------------------------------------------------------------------
// Projection (unchanged from R16). 1024 thr; block = 64 x-rows; grid 256.
// ---------------------------------------------------------------------------
__global__ __launch_bounds__(1024)
__attribute__((amdgpu_waves_per_eu(4, 4)))
void proj_kernel(
    const float* __restrict__ x,  const float* __restrict__ Wq,
    const float* __restrict__ Wk, const float* __restrict__ Wv,
    unsigned short* __restrict__ qb, unsigned short* __restrict__ kb,
    unsigned short* __restrict__ vf)
{
    __shared__ float xs[64][66];
    __shared__ __align__(16) unsigned short Wh[96][76], Wl[96][76];

    const int bid  = blockIdx.x;
    const int tid  = threadIdx.x;
    const int w    = tid >> 6;
    const int lane = tid & 63;
    const int col  = lane & 31;
    const int g    = lane >> 5;

    {
        const float* xblk = x + (size_t)bid * 64 * 64;
        const int fi = tid * 4;
        fvec4 v = *(const fvec4*)(xblk + fi);
        const int r = fi >> 6, c = fi & 63;
        xs[r][c + 0] = v[0]; xs[r][c + 1] = v[1];
        xs[r][c + 2] = v[2]; xs[r][c + 3] = v[3];
    }
    const float SCQ = 0.25f * 1.44269504088896340736f; // 1/sqrt(16)*log2(e)
    {
        const int n = tid & 15, k = tid >> 4;          // Wq: 1 value/thread
        float wv = Wq[tid] * SCQ;
        unsigned short h = f2bf(wv);
        Wh[n][k] = h;
        Wl[n][k] = f2bf(wv - __uint_as_float((unsigned)h << 16));
    }
    {
        const int n = tid & 15, k = tid >> 4;          // Wk: 1 value/thread
        float wv = Wk[tid];
        unsigned short h = f2bf(wv);
        Wh[16 + n][k] = h;
        Wl[16 + n][k] = f2bf(wv - __uint_as_float((unsigned)h << 16));
    }
    #pragma unroll
    for (int j = 0; j < 4; ++j) {                      // Wv: 4 values/thread
        const int idx = tid + 1024 * j;
        const int n = idx & 63, k = idx >> 6;
        float wv = Wv[idx];
        unsigned short h = f2bf(wv);
        Wh[32 + n][k] = h;
        Wl[32 + n][k] = f2bf(wv - __uint_as_float((unsigned)h << 16));
    }
    __syncthreads();

    if (w < 6) {
        const int nt = w >> 1;            // 0: q/k, 1: v lo, 2: v hi
        const int rh = w & 1;             // which 32-row half
        const int row0 = bid * 64 + rh * 32;
        const int lrow = rh * 32 + col;

        s16x8 xh[4], xl[4];
        #pragma unroll
        for (int kc = 0; kc < 4; ++kc) {
            const float* xp = &xs[lrow][kc * 16 + 8 * g];
            float2 a0 = *(const float2*)(xp + 0);
            float2 a1 = *(const float2*)(xp + 2);
            float2 a2 = *(const float2*)(xp + 4);
            float2 a3 = *(const float2*)(xp + 6);
            I4S8 uh, ul;
            uh.i[0] = cvt_pk_bf16(a0.x, a0.y);
            uh.i[1] = cvt_pk_bf16(a1.x, a1.y);
            uh.i[2] = cvt_pk_bf16(a2.x, a2.y);
            uh.i[3] = cvt_pk_bf16(a3.x, a3.y);
            ul.i[0] = cvt_pk_bf16(a0.x - __uint_as_float((unsigned)uh.i[0] << 16),
                                  a0.y - __uint_as_float((unsigned)uh.i[0] & 0xffff0000u));
            ul.i[1] = cvt_pk_bf16(a1.x - __uint_as_float((unsigned)uh.i[1] << 16),
                                  a1.y - __uint_as_float((unsigned)uh.i[1] & 0xffff0000u));
            ul.i[2] = cvt_pk_bf16(a2.x - __uint_as_float((unsigned)uh.i[2] << 16),
                                  a2.y - __uint_as_float((unsigned)uh.i[2] & 0xffff0000u));
            ul.i[3] = cvt_pk_bf16(a3.x - __uint_as_float((unsigned)uh.i[3] << 16),
                                  a3.y - __uint_as_float((unsigned)uh.i[3] & 0xffff0000u));
            xh[kc] = uh.v; xl[kc] = ul.v;
        }

        f32x16 acc = (f32x16)0.0f;
        const int n = nt * 32 + col;
        #pragma unroll
        for (int kc = 0; kc < 4; ++kc) {
            const int off = kc * 16 + 8 * g;
            s16x8 bh = cat4(*(const s16x4*)&Wh[n][off], *(const s16x4*)&Wh[n][off + 4]);
            s16x8 bl = cat4(*(const s16x4*)&Wl[n][off], *(const s16x4*)&Wl[n][off + 4]);
            acc = __builtin_amdgcn_mfma_f32_32x32x16_bf16(xh[kc], bh, acc, 0, 0, 0);
            acc = __builtin_amdgcn_mfma_f32_32x32x16_bf16(xl[kc], bh, acc, 0, 0, 0);
            acc = __builtin_amdgcn_mfma_f32_32x32x16_bf16(xh[kc], bl, acc, 0, 0, 0);
        }

        if (nt == 0) {
            unsigned short* dst = (col < 16) ? (qb + col) : (kb + (col - 16));
            #pragma unroll
            for (int rr = 0; rr < 16; ++rr) {
                const int grow = row0 + (rr & 3) + 8 * (rr >> 2) + 4 * g;
                dst[(size_t)grow * 16] = f2bf(acc[rr]);
            }
        } else {
            const int mt = nt - 1;
            unsigned short* const vtile = vf + (size_t)bid * 4096;
            #pragma unroll
            for (int ci = 0; ci < 2; ++ci) {
                I4S8 pk;
                pk.i[0] = cvt_pk_bf16(acc[8*ci + 0], acc[8*ci + 1]);
                pk.i[1] = cvt_pk_bf16(acc[8*ci + 2], acc[8*ci + 3]);
                pk.i[2] = cvt_pk_bf16(acc[8*ci + 4], acc[8*ci + 5]);
                pk.i[3] = cvt_pk_bf16(acc[8*ci + 6], acc[8*ci + 7]);
                const int c = 2 * rh + ci;
                *(s16x8*)(vtile + ((c * 2 + mt) * 64 + lane) * 8) = pk.v;
            }
        }
    }
}

// ---------------------------------------------------------------------------
// Single 32-key tile (R16). DIAG: triangular mask.
// ---------------------------------------------------------------------------
template<bool DIAG>
static __device__ __forceinline__ void do_tile32(
    const unsigned short* kp, const unsigned short* vt, const int lane,
    const s16x8 qf, const s16x8 ones, const int col, const int g,
    f32x16& o0, f32x16& o1, f32x16& osum)
{
    s16x8 kf   = *(const s16x8*)(kp);
    s16x8 va00 = *(const s16x8*)(vt + (0 * 64 + lane) * 8);
    s16x8 va01 = *(const s16x8*)(vt + (1 * 64 + lane) * 8);
    s16x8 va10 = *(const s16x8*)(vt + (2 * 64 + lane) * 8);
    s16x8 va11 = *(const s16x8*)(vt + (3 * 64 + lane) * 8);

    f32x16 s = __builtin_amdgcn_mfma_f32_32x32x16_bf16(kf, qf, (f32x16)0.0f, 0, 0, 0);

    #pragma unroll
    for (int rr = 0; rr < 16; ++rr) {
        float ev = __builtin_amdgcn_exp2f(s[rr]);
        if (DIAG) {
            const int drow = (rr & 3) + 8 * (rr >> 2) + 4 * g;
            ev = (drow <= col) ? ev : 0.f;
        }
        s[rr] = ev;
    }

    I4S8 pa, pb;
    pa.i[0] = cvt_pk_bf16(s[0],  s[1]);
    pa.i[1] = cvt_pk_bf16(s[2],  s[3]);
    pa.i[2] = cvt_pk_bf16(s[4],  s[5]);
    pa.i[3] = cvt_pk_bf16(s[6],  s[7]);
    pb.i[0] = cvt_pk_bf16(s[8],  s[9]);
    pb.i[1] = cvt_pk_bf16(s[10], s[11]);
    pb.i[2] = cvt_pk_bf16(s[12], s[13]);
    pb.i[3] = cvt_pk_bf16(s[14], s[15]);

    o0   = __builtin_amdgcn_mfma_f32_32x32x16_bf16(va00, pa.v, o0,   0, 0, 0);
    o1   = __builtin_amdgcn_mfma_f32_32x32x16_bf16(va01, pa.v, o1,   0, 0, 0);
    osum = __builtin_amdgcn_mfma_f32_32x32x16_bf16(ones, pa.v, osum, 0, 0, 0);
    o0   = __builtin_amdgcn_mfma_f32_32x32x16_bf16(va10, pb.v, o0,   0, 0, 0);
    o1   = __builtin_amdgcn_mfma_f32_32x32x16_bf16(va11, pb.v, o1,   0, 0, 0);
    osum = __builtin_amdgcn_mfma_f32_32x32x16_bf16(ones, pb.v, osum, 0, 0, 0);
}

// ---------------------------------------------------------------------------
// Two interleaved full tiles (tA, tB): independent K/V/S/P state, shared
// accumulators. B's MFMAs cover A's exp2/cvt VALU and vice versa; the
// compiler can schedule across the two dependency chains freely.
// ---------------------------------------------------------------------------
static __device__ __forceinline__ void do_pair32(
    const unsigned short* kpA, const unsigned short* vtA,
    const unsigned short* kpB, const unsigned short* vtB, const int lane,
    const s16x8 qf, const s16x8 ones,
    f32x16& o0, f32x16& o1, f32x16& osum)
{
    s16x8 kfA = *(const s16x8*)(kpA);
    s16x8 kfB = *(const s16x8*)(kpB);
    s16x8 vaA0 = *(const s16x8*)(vtA + (0 * 64 + lane) * 8);
    s16x8 vaA1 = *(const s16x8*)(vtA + (1 * 64 + lane) * 8);
    s16x8 vaA2 = *(const s16x8*)(vtA + (2 * 64 + lane) * 8);
    s16x8 vaA3 = *(const s16x8*)(vtA + (3 * 64 + lane) * 8);
    s16x8 vaB0 = *(const s16x8*)(vtB + (0 * 64 + lane) * 8);
    s16x8 vaB1 = *(const s16x8*)(vtB + (1 * 64 + lane) * 8);
    s16x8 vaB2 = *(const s16x8*)(vtB + (2 * 64 + lane) * 8);
    s16x8 vaB3 = *(const s16x8*)(vtB + (3 * 64 + lane) * 8);

    f32x16 sA = __builtin_amdgcn_mfma_f32_32x32x16_bf16(kfA, qf, (f32x16)0.0f, 0, 0, 0);
    f32x16 sB = __builtin_amdgcn_mfma_f32_32x32x16_bf16(kfB, qf, (f32x16)0.0f, 0, 0, 0);

    // A softmax (overlaps B's QK in the MFMA pipe)
    #pragma unroll
    for (int rr = 0; rr < 16; ++rr) sA[rr] = __builtin_amdgcn_exp2f(sA[rr]);
    I4S8 paA, pbA;
    paA.i[0] = cvt_pk_bf16(sA[0],  sA[1]);
    paA.i[1] = cvt_pk_bf16(sA[2],  sA[3]);
    paA.i[2] = cvt_pk_bf16(sA[4],  sA[5]);
    paA.i[3] = cvt_pk_bf16(sA[6],  sA[7]);
    pbA.i[0] = cvt_pk_bf16(sA[8],  sA[9]);
    pbA.i[1] = cvt_pk_bf16(sA[10], sA[11]);
    pbA.i[2] = cvt_pk_bf16(sA[12], sA[13]);
    pbA.i[3] = cvt_pk_bf16(sA[14], sA[15]);

    // A PV (MFMA pipe) while B softmax (VALU) runs
    o0   = __builtin_amdgcn_mfma_f32_32x32x16_bf16(vaA0, paA.v, o0,   0, 0, 0);
    o1   = __builtin_amdgcn_mfma_f32_32x32x16_bf16(vaA1, paA.v, o1,   0, 0, 0);
    osum = __builtin_amdgcn_mfma_f32_32x32x16_bf16(ones, paA.v, osum, 0, 0, 0);

    #pragma unroll
    for (int rr = 0; rr < 16; ++rr) sB[rr] = __builtin_amdgcn_exp2f(sB[rr]);
    I4S8 paB, pbB;
    paB.i[0] = cvt_pk_bf16(sB[0],  sB[1]);
    paB.i[1] = cvt_pk_bf16(sB[2],  sB[3]);
    paB.i[2] = cvt_pk_bf16(sB[4],  sB[5]);
    paB.i[3] = cvt_pk_bf16(sB[6],  sB[7]);
    pbB.i[0] = cvt_pk_bf16(sB[8],  sB[9]);
    pbB.i[1] = cvt_pk_bf16(sB[10], sB[11]);
    pbB.i[2] = cvt_pk_bf16(sB[12], sB[13]);
    pbB.i[3] = cvt_pk_bf16(sB[14], sB[15]);

    o0   = __builtin_amdgcn_mfma_f32_32x32x16_bf16(vaA2, pbA.v, o0,   0, 0, 0);
    o1   = __builtin_amdgcn_mfma_f32_32x32x16_bf16(vaA3, pbA.v, o1,   0, 0, 0);
    osum = __builtin_amdgcn_mfma_f32_32x32x16_bf16(ones, pbA.v, osum, 0, 0, 0);
    o0   = __builtin_amdgcn_mfma_f32_32x32x16_bf16(vaB0, paB.v, o0,   0, 0, 0);
    o1   = __builtin_amdgcn_mfma_f32_32x32x16_bf16(vaB1, paB.v, o1,   0, 0, 0);
    osum = __builtin_amdgcn_mfma_f32_32x32x16_bf16(ones, paB.v, osum, 0, 0, 0);
    o0   = __builtin_amdgcn_mfma_f32_32x32x16_bf16(vaB2, pbB.v, o0,   0, 0, 0);
    o1   = __builtin_amdgcn_mfma_f32_32x32x16_bf16(vaB3, pbB.v, o1,   0, 0, 0);
    osum = __builtin_amdgcn_mfma_f32_32x32x16_bf16(ones, pbB.v, osum, 0, 0, 0);
}

// ---------------------------------------------------------------------------
// Flash attention. 1024 thr = 16 waves; grid (64, NBATCH). Block p does
// q-tiles p and 127-p: 129 32-key tiles. Wave w: t = w, w+16, ... (paired
// two-at-a-time); tile t == i is the triangular diagonal. Sum merge.
// ---------------------------------------------------------------------------
__global__ __launch_bounds__(1024)
__attribute__((amdgpu_waves_per_eu(4, 4)))
void attn_kernel(
    const unsigned short* __restrict__ qb, const unsigned short* __restrict__ kb,
    const unsigned short* __restrict__ vf, float* __restrict__ out)
{
    __shared__ float pl[16][32];
    __shared__ float pO[2048 * 17];      // [dv*32+q]*17 + w; stride 17 = conflict-free
    __shared__ float outS[32][66];       // store bounce (coalescing)

    const int tid  = threadIdx.x;
    const int w    = tid >> 6;
    const int lane = tid & 63;
    const int col  = lane & 31;
    const int g    = lane >> 5;
    const int b    = blockIdx.y;
    const int p    = blockIdx.x;

    I4S8 onesu;
    onesu.i[0] = 0x3F803F80; onesu.i[1] = 0x3F803F80;
    onesu.i[2] = 0x3F803F80; onesu.i[3] = 0x3F803F80;
    const s16x8 ones = onesu.v;

    const unsigned short* const kbase = kb + (size_t)b * TSEQ * 16 + (size_t)col * 16 + 8 * g;
    const unsigned short* const vbase = vf + (size_t)b * 64 * 4096;

    for (int half = 0; half < 2; ++half) {
        const int i  = half ? (127 - p) : p;
        const int q0 = i * 32;

        const s16x8 qf = *(const s16x8*)(qb + ((size_t)(b * TSEQ) + q0 + col) * 16 + 8 * g);

        f32x16 o0 = (f32x16)0.0f, o1 = (f32x16)0.0f, osum = (f32x16)0.0f;

        int t = w;
        // paired full tiles: both t and t+16 strictly below the diagonal
        for (; t + 16 < i; t += 32) {
            const int tB = t + 16;
            do_pair32(kbase + (size_t)t  * 512,
                      vbase + (size_t)(t  >> 1) * 4096 + (t  & 1) * 2048,
                      kbase + (size_t)tB * 512,
                      vbase + (size_t)(tB >> 1) * 4096 + (tB & 1) * 2048,
                      lane, qf, ones, o0, o1, osum);
        }
        if (t < i) {                         // leftover full tile
            do_tile32<false>(kbase + (size_t)t * 512,
                             vbase + (size_t)(t >> 1) * 4096 + (t & 1) * 2048,
                             lane, qf, ones, col, g, o0, o1, osum);
            t += 16;
        }
        if (t == i) {                        // this wave owns the diagonal tile
            do_tile32<true>(kbase + (size_t)t * 512,
                            vbase + (size_t)(t >> 1) * 4096 + (t & 1) * 2048,
                            lane, qf, ones, col, g, o0, o1, osum);
        }

        // -- write partials (osum[0] = full 32-key row sum; idle waves 0)
        if (g == 0) pl[w][col] = osum[0];
        #pragma unroll
        for (int mt = 0; mt < 2; ++mt) {
            const f32x16 oa = mt ? o1 : o0;
            #pragma unroll
            for (int rr = 0; rr < 16; ++rr) {
                const int dv = mt * 32 + (rr & 3) + 8 * (rr >> 2) + 4 * g;
                pO[(dv * 32 + col) * 17 + w] = oa[rr];
            }
        }
        __syncthreads();

        // -- 16-way sum merge: thread handles (q = tid&31, dv = tid>>5 [+32])
        {
            const int q   = tid & 31;
            const int dvh = tid >> 5;
            float L = 0.f;
            #pragma unroll
            for (int ww = 0; ww < 16; ++ww) L += pl[ww][q];
            const float inv = 1.0f / L;
            #pragma unroll
            for (int pass = 0; pass < 2; ++pass) {
                const int dv = dvh + 32 * pass;
                const float* prow = &pO[(dv * 32 + q) * 17];
                float sA = 0.f, sB = 0.f;
                #pragma unroll
                for (int c = 0; c < 8; ++c) { sA += prow[2*c]; sB += prow[2*c+1]; }
                outS[q][dv] = (sA + sB) * inv;
            }
        }
        __syncthreads();

        // -- coalesced store: thread (q2 = tid>>5, dvp = (tid&31)*2)
        {
            const int q2  = tid >> 5;
            const int dvp = (tid & 31) * 2;
            float2 v2 = *(const float2*)&outS[q2][dvp];
            *(float2*)(out + ((size_t)(b * TSEQ) + q0 + q2) * 64 + dvp) = v2;
        }
        // pO reuse in next half is safe: reads completed before the barrier.
    }
}

// ---------------------------------------------------------------------------
extern "C" void kernel_launch(void* const* d_in, const int* in_sizes, int n_in,
                              void* d_out, int out_size, void* d_ws, size_t ws_size,
                              hipStream_t stream) {
    const float* x  = (const float*)d_in[0];
    const float* Wq = (const float*)d_in[1];
    const float* Wk = (const float*)d_in[2];
    const float* Wv = (const float*)d_in[3];

    // workspace: q (512KiB) | k (512KiB) | v-fragments (2MiB) = 3 MiB
    unsigned short* qb = (unsigned short*)d_ws;
    unsigned short* kb = qb + (size_t)NBATCH * TSEQ * 16;
    unsigned short* vf = kb + (size_t)NBATCH * TSEQ * 16;
    float* out = (float*)d_out;

    proj_kernel<<<dim3((NBATCH * TSEQ) / 64), 1024, 0, stream>>>(x, Wq, Wk, Wv, qb, kb, vf);
    attn_kernel<<<dim3(64, NBATCH), 1024, 0, stream>>>(qb, kb, vf, out);
}

// Round 18
// 23.211 us; speedup vs baseline: 1.2184x; 1.2184x over previous
//
#include <hip/hip_runtime.h>

// SelfAttention: x[4,4096,64] f32; Wq,Wk[64,16]; Wv[64,64]; out[4,4096,64] f32.
// R18 = R16 base (R17's two-tile interleave reverted: 2x tile state spilled,
//   28.3us) + three cuts:
//   1) merge partials packed bf16 (pO 139->69KB, one-pass merge: each int
//      carries an adjacent dv pair; d0 is always even in the D-layout),
//   2) strength-reduced tile addressing (kp += 8192, vt += 32768; t&1,t>>1
//      are loop-affine),
//   3) unchanged: osum=P*ones MFMA denominator, pair-balanced blocks
//      (129 32-key tiles), no-max exp2 flash, 1024-thr proj.

#define TSEQ 4096
#define NBATCH 4

typedef __attribute__((ext_vector_type(4)))  float fvec4;
typedef __attribute__((ext_vector_type(16))) float f32x16;
typedef __attribute__((ext_vector_type(4)))  short s16x4;
typedef __attribute__((ext_vector_type(8)))  short s16x8;

union I4S8 { int i[4]; s16x8 v; };

static __device__ __forceinline__ unsigned short f2bf(float f) {
    unsigned u = __float_as_uint(f);
    u += 0x7FFFu + ((u >> 16) & 1u);   // RNE
    return (unsigned short)(u >> 16);
}

static __device__ __forceinline__ int cvt_pk_bf16(float lo, float hi) {
    int r;
    asm("v_cvt_pk_bf16_f32 %0, %1, %2" : "=v"(r) : "v"(lo), "v"(hi));
    return r;
}

static __device__ __forceinline__ s16x8 cat4(s16x4 a, s16x4 b) {
    return __builtin_shufflevector(a, b, 0, 1, 2, 3, 4, 5, 6, 7);
}

// ---------------------------------------------------------------------------
// Projection (unchanged from R16). 1024 thr; block = 64 x-rows; grid 256.
// ---------------------------------------------------------------------------
__global__ __launch_bounds__(1024)
__attribute__((amdgpu_waves_per_eu(4, 4)))
void proj_kernel(
    const float* __restrict__ x,  const float* __restrict__ Wq,
    const float* __restrict__ Wk, const float* __restrict__ Wv,
    unsigned short* __restrict__ qb, unsigned short* __restrict__ kb,
    unsigned short* __restrict__ vf)
{
    __shared__ float xs[64][66];
    __shared__ __align__(16) unsigned short Wh[96][76], Wl[96][76];

    const int bid  = blockIdx.x;
    const int tid  = threadIdx.x;
    const int w    = tid >> 6;
    const int lane = tid & 63;
    const int col  = lane & 31;
    const int g    = lane >> 5;

    {
        const float* xblk = x + (size_t)bid * 64 * 64;
        const int fi = tid * 4;
        fvec4 v = *(const fvec4*)(xblk + fi);
        const int r = fi >> 6, c = fi & 63;
        xs[r][c + 0] = v[0]; xs[r][c + 1] = v[1];
        xs[r][c + 2] = v[2]; xs[r][c + 3] = v[3];
    }
    const float SCQ = 0.25f * 1.44269504088896340736f; // 1/sqrt(16)*log2(e)
    {
        const int n = tid & 15, k = tid >> 4;          // Wq: 1 value/thread
        float wv = Wq[tid] * SCQ;
        unsigned short h = f2bf(wv);
        Wh[n][k] = h;
        Wl[n][k] = f2bf(wv - __uint_as_float((unsigned)h << 16));
    }
    {
        const int n = tid & 15, k = tid >> 4;          // Wk: 1 value/thread
        float wv = Wk[tid];
        unsigned short h = f2bf(wv);
        Wh[16 + n][k] = h;
        Wl[16 + n][k] = f2bf(wv - __uint_as_float((unsigned)h << 16));
    }
    #pragma unroll
    for (int j = 0; j < 4; ++j) {                      // Wv: 4 values/thread
        const int idx = tid + 1024 * j;
        const int n = idx & 63, k = idx >> 6;
        float wv = Wv[idx];
        unsigned short h = f2bf(wv);
        Wh[32 + n][k] = h;
        Wl[32 + n][k] = f2bf(wv - __uint_as_float((unsigned)h << 16));
    }
    __syncthreads();

    if (w < 6) {
        const int nt = w >> 1;            // 0: q/k, 1: v lo, 2: v hi
        const int rh = w & 1;             // which 32-row half
        const int row0 = bid * 64 + rh * 32;
        const int lrow = rh * 32 + col;

        s16x8 xh[4], xl[4];
        #pragma unroll
        for (int kc = 0; kc < 4; ++kc) {
            const float* xp = &xs[lrow][kc * 16 + 8 * g];
            float2 a0 = *(const float2*)(xp + 0);
            float2 a1 = *(const float2*)(xp + 2);
            float2 a2 = *(const float2*)(xp + 4);
            float2 a3 = *(const float2*)(xp + 6);
            I4S8 uh, ul;
            uh.i[0] = cvt_pk_bf16(a0.x, a0.y);
            uh.i[1] = cvt_pk_bf16(a1.x, a1.y);
            uh.i[2] = cvt_pk_bf16(a2.x, a2.y);
            uh.i[3] = cvt_pk_bf16(a3.x, a3.y);
            ul.i[0] = cvt_pk_bf16(a0.x - __uint_as_float((unsigned)uh.i[0] << 16),
                                  a0.y - __uint_as_float((unsigned)uh.i[0] & 0xffff0000u));
            ul.i[1] = cvt_pk_bf16(a1.x - __uint_as_float((unsigned)uh.i[1] << 16),
                                  a1.y - __uint_as_float((unsigned)uh.i[1] & 0xffff0000u));
            ul.i[2] = cvt_pk_bf16(a2.x - __uint_as_float((unsigned)uh.i[2] << 16),
                                  a2.y - __uint_as_float((unsigned)uh.i[2] & 0xffff0000u));
            ul.i[3] = cvt_pk_bf16(a3.x - __uint_as_float((unsigned)uh.i[3] << 16),
                                  a3.y - __uint_as_float((unsigned)uh.i[3] & 0xffff0000u));
            xh[kc] = uh.v; xl[kc] = ul.v;
        }

        f32x16 acc = (f32x16)0.0f;
        const int n = nt * 32 + col;
        #pragma unroll
        for (int kc = 0; kc < 4; ++kc) {
            const int off = kc * 16 + 8 * g;
            s16x8 bh = cat4(*(const s16x4*)&Wh[n][off], *(const s16x4*)&Wh[n][off + 4]);
            s16x8 bl = cat4(*(const s16x4*)&Wl[n][off], *(const s16x4*)&Wl[n][off + 4]);
            acc = __builtin_amdgcn_mfma_f32_32x32x16_bf16(xh[kc], bh, acc, 0, 0, 0);
            acc = __builtin_amdgcn_mfma_f32_32x32x16_bf16(xl[kc], bh, acc, 0, 0, 0);
            acc = __builtin_amdgcn_mfma_f32_32x32x16_bf16(xh[kc], bl, acc, 0, 0, 0);
        }

        if (nt == 0) {
            unsigned short* dst = (col < 16) ? (qb + col) : (kb + (col - 16));
            #pragma unroll
            for (int rr = 0; rr < 16; ++rr) {
                const int grow = row0 + (rr & 3) + 8 * (rr >> 2) + 4 * g;
                dst[(size_t)grow * 16] = f2bf(acc[rr]);
            }
        } else {
            const int mt = nt - 1;
            unsigned short* const vtile = vf + (size_t)bid * 4096;
            #pragma unroll
            for (int ci = 0; ci < 2; ++ci) {
                I4S8 pk;
                pk.i[0] = cvt_pk_bf16(acc[8*ci + 0], acc[8*ci + 1]);
                pk.i[1] = cvt_pk_bf16(acc[8*ci + 2], acc[8*ci + 3]);
                pk.i[2] = cvt_pk_bf16(acc[8*ci + 4], acc[8*ci + 5]);
                pk.i[3] = cvt_pk_bf16(acc[8*ci + 6], acc[8*ci + 7]);
                const int c = 2 * rh + ci;
                *(s16x8*)(vtile + ((c * 2 + mt) * 64 + lane) * 8) = pk.v;
            }
        }
    }
}

// ---------------------------------------------------------------------------
// One 32-key tile (R16). DIAG: triangular mask. osum = P*ones denominator.
// ---------------------------------------------------------------------------
template<bool DIAG>
static __device__ __forceinline__ void do_tile32(
    const unsigned short* kp, const unsigned short* vt, const int lane,
    const s16x8 qf, const s16x8 ones, const int col, const int g,
    f32x16& o0, f32x16& o1, f32x16& osum)
{
    s16x8 kf   = *(const s16x8*)(kp);
    s16x8 va00 = *(const s16x8*)(vt + (0 * 64 + lane) * 8);
    s16x8 va01 = *(const s16x8*)(vt + (1 * 64 + lane) * 8);
    s16x8 va10 = *(const s16x8*)(vt + (2 * 64 + lane) * 8);
    s16x8 va11 = *(const s16x8*)(vt + (3 * 64 + lane) * 8);

    f32x16 s = __builtin_amdgcn_mfma_f32_32x32x16_bf16(kf, qf, (f32x16)0.0f, 0, 0, 0);

    #pragma unroll
    for (int rr = 0; rr < 16; ++rr) {
        float ev = __builtin_amdgcn_exp2f(s[rr]);
        if (DIAG) {
            const int drow = (rr & 3) + 8 * (rr >> 2) + 4 * g;
            ev = (drow <= col) ? ev : 0.f;
        }
        s[rr] = ev;
    }

    I4S8 pa, pb;
    pa.i[0] = cvt_pk_bf16(s[0],  s[1]);
    pa.i[1] = cvt_pk_bf16(s[2],  s[3]);
    pa.i[2] = cvt_pk_bf16(s[4],  s[5]);
    pa.i[3] = cvt_pk_bf16(s[6],  s[7]);
    pb.i[0] = cvt_pk_bf16(s[8],  s[9]);
    pb.i[1] = cvt_pk_bf16(s[10], s[11]);
    pb.i[2] = cvt_pk_bf16(s[12], s[13]);
    pb.i[3] = cvt_pk_bf16(s[14], s[15]);

    o0   = __builtin_amdgcn_mfma_f32_32x32x16_bf16(va00, pa.v, o0,   0, 0, 0);
    o1   = __builtin_amdgcn_mfma_f32_32x32x16_bf16(va01, pa.v, o1,   0, 0, 0);
    osum = __builtin_amdgcn_mfma_f32_32x32x16_bf16(ones, pa.v, osum, 0, 0, 0);
    o0   = __builtin_amdgcn_mfma_f32_32x32x16_bf16(va10, pb.v, o0,   0, 0, 0);
    o1   = __builtin_amdgcn_mfma_f32_32x32x16_bf16(va11, pb.v, o1,   0, 0, 0);
    osum = __builtin_amdgcn_mfma_f32_32x32x16_bf16(ones, pb.v, osum, 0, 0, 0);
}

// ---------------------------------------------------------------------------
// Flash attention. 1024 thr = 16 waves; grid (64, NBATCH). Block p does
// q-tiles p and 127-p: 129 32-key tiles. Wave w: t = w, w+16, ... with
// incremental pointers (t&1, t>>1 are loop-affine). Partials merged 16-way
// through packed-bf16 LDS (one-pass merge: each int = adjacent dv pair).
// ---------------------------------------------------------------------------
__global__ __launch_bounds__(1024)
__attribute__((amdgpu_waves_per_eu(4, 4)))
void attn_kernel(
    const unsigned short* __restrict__ qb, const unsigned short* __restrict__ kb,
    const unsigned short* __restrict__ vf, float* __restrict__ out)
{
    __shared__ float pl[16][32];
    __shared__ int   pOi[1024 * 17];     // [dvp*32+q]*17 + w; packed bf16 pairs
    __shared__ float outS[32][66];       // store bounce (coalescing)

    const int tid  = threadIdx.x;
    const int w    = tid >> 6;
    const int lane = tid & 63;
    const int col  = lane & 31;
    const int g    = lane >> 5;
    const int b    = blockIdx.y;
    const int p    = blockIdx.x;

    I4S8 onesu;
    onesu.i[0] = 0x3F803F80; onesu.i[1] = 0x3F803F80;
    onesu.i[2] = 0x3F803F80; onesu.i[3] = 0x3F803F80;
    const s16x8 ones = onesu.v;

    const unsigned short* const kbase = kb + (size_t)b * TSEQ * 16 + (size_t)col * 16 + 8 * g;
    const unsigned short* const vbase = vf + (size_t)b * 64 * 4096
                                      + (size_t)(w >> 1) * 4096 + (w & 1) * 2048;

    for (int half = 0; half < 2; ++half) {
        const int i  = half ? (127 - p) : p;
        const int q0 = i * 32;

        const s16x8 qf = *(const s16x8*)(qb + ((size_t)(b * TSEQ) + q0 + col) * 16 + 8 * g);

        f32x16 o0 = (f32x16)0.0f, o1 = (f32x16)0.0f, osum = (f32x16)0.0f;

        // incremental tile pointers: t = w + 16k -> kp += 16*512, vt += 8*4096
        const unsigned short* kp = kbase + (size_t)w * 512;
        const unsigned short* vt = vbase;
        int t = w;
        for (; t < i; t += 16) {             // full 32-key tiles
            do_tile32<false>(kp, vt, lane, qf, ones, col, g, o0, o1, osum);
            kp += 8192; vt += 32768;
        }
        if (t == i) {                        // this wave owns the diagonal tile
            do_tile32<true>(kp, vt, lane, qf, ones, col, g, o0, o1, osum);
        }

        // -- write partials: lsum f32; O as packed bf16 dv-pairs (d0 even)
        if (g == 0) pl[w][col] = osum[0];
        #pragma unroll
        for (int mt = 0; mt < 2; ++mt) {
            const f32x16 oa = mt ? o1 : o0;
            #pragma unroll
            for (int j = 0; j < 8; ++j) {
                const int rr = 2 * j;
                const int d0 = mt * 32 + (rr & 3) + 8 * (rr >> 2) + 4 * g;
                pOi[((d0 >> 1) * 32 + col) * 17 + w] = cvt_pk_bf16(oa[rr], oa[rr + 1]);
            }
        }
        __syncthreads();

        // -- one-pass 16-way merge: thread (q = tid&31, dvp = tid>>5)
        {
            const int q   = tid & 31;
            const int dvp = tid >> 5;        // dv pair index 0..31
            float L = 0.f;
            #pragma unroll
            for (int ww = 0; ww < 16; ++ww) L += pl[ww][q];
            const float inv = 1.0f / L;
            const int* prow = &pOi[(dvp * 32 + q) * 17];
            float sA = 0.f, sB = 0.f;
            #pragma unroll
            for (int c = 0; c < 16; ++c) {
                const int v = prow[c];
                sA += __uint_as_float((unsigned)v << 16);
                sB += __uint_as_float((unsigned)v & 0xffff0000u);
            }
            outS[q][2 * dvp + 0] = sA * inv;
            outS[q][2 * dvp + 1] = sB * inv;
        }
        __syncthreads();

        // -- coalesced store: thread (q2 = tid>>5, dvq = (tid&31)*2)
        {
            const int q2  = tid >> 5;
            const int dvq = (tid & 31) * 2;
            float2 v2 = *(const float2*)&outS[q2][dvq];
            *(float2*)(out + ((size_t)(b * TSEQ) + q0 + q2) * 64 + dvq) = v2;
        }
        // pOi reuse in next half is safe: reads completed before the barrier.
    }
}

// ---------------------------------------------------------------------------
extern "C" void kernel_launch(void* const* d_in, const int* in_sizes, int n_in,
                              void* d_out, int out_size, void* d_ws, size_t ws_size,
                              hipStream_t stream) {
    const float* x  = (const float*)d_in[0];
    const float* Wq = (const float*)d_in[1];
    const float* Wk = (const float*)d_in[2];
    const float* Wv = (const float*)d_in[3];

    // workspace: q (512KiB) | k (512KiB) | v-fragments (2MiB) = 3 MiB
    unsigned short* qb = (unsigned short*)d_ws;
    unsigned short* kb = qb + (size_t)NBATCH * TSEQ * 16;
    unsigned short* vf = kb + (size_t)NBATCH * TSEQ * 16;
    float* out = (float*)d_out;

    proj_kernel<<<dim3((NBATCH * TSEQ) / 64), 1024, 0, stream>>>(x, Wq, Wk, Wv, qb, kb, vf);
    attn_kernel<<<dim3(64, NBATCH), 1024, 0, stream>>>(qb, kb, vf, out);
}

// Round 19
// 22.142 us; speedup vs baseline: 1.2772x; 1.0482x over previous
//
#include <hip/hip_runtime.h>

// SelfAttention: x[4,4096,64] f32; Wq,Wk[64,16]; Wv[64,64]; out[4,4096,64] f32.
// R19 = R18 + attn register diet. Theory: at 4 waves/SIMD the unified V+A
//   budget is 128/wave; R18's demand (48 AGPR acc incl. osum + 40 in-flight
//   load regs + s 16 + P 8 + addr ~16) = ~128 -> allocator shuttles loads
//   through AGPRs (v_accvgpr moves ~80/tile), explaining VALUBusy 54% at 5x
//   the source-op count. Cuts: drop osum (-16 AGPR, -2 MFMA/tile; VALU sums
//   + one shfl instead) and stagger V loads (va10/11 issued after QK MFMA).
//   Demand ~104 < 128 -> no shuttling.
// Unchanged: packed-bf16 one-pass merge, strength-reduced tile pointers,
//   pair-balanced blocks (129 32-key tiles), no-max exp2 flash, 1024-thr proj.

#define TSEQ 4096
#define NBATCH 4

typedef __attribute__((ext_vector_type(4)))  float fvec4;
typedef __attribute__((ext_vector_type(16))) float f32x16;
typedef __attribute__((ext_vector_type(4)))  short s16x4;
typedef __attribute__((ext_vector_type(8)))  short s16x8;

union I4S8 { int i[4]; s16x8 v; };

static __device__ __forceinline__ unsigned short f2bf(float f) {
    unsigned u = __float_as_uint(f);
    u += 0x7FFFu + ((u >> 16) & 1u);   // RNE
    return (unsigned short)(u >> 16);
}

static __device__ __forceinline__ int cvt_pk_bf16(float lo, float hi) {
    int r;
    asm("v_cvt_pk_bf16_f32 %0, %1, %2" : "=v"(r) : "v"(lo), "v"(hi));
    return r;
}

static __device__ __forceinline__ s16x8 cat4(s16x4 a, s16x4 b) {
    return __builtin_shufflevector(a, b, 0, 1, 2, 3, 4, 5, 6, 7);
}

// ---------------------------------------------------------------------------
// Projection (unchanged from R16). 1024 thr; block = 64 x-rows; grid 256.
// ---------------------------------------------------------------------------
__global__ __launch_bounds__(1024)
__attribute__((amdgpu_waves_per_eu(4, 4)))
void proj_kernel(
    const float* __restrict__ x,  const float* __restrict__ Wq,
    const float* __restrict__ Wk, const float* __restrict__ Wv,
    unsigned short* __restrict__ qb, unsigned short* __restrict__ kb,
    unsigned short* __restrict__ vf)
{
    __shared__ float xs[64][66];
    __shared__ __align__(16) unsigned short Wh[96][76], Wl[96][76];

    const int bid  = blockIdx.x;
    const int tid  = threadIdx.x;
    const int w    = tid >> 6;
    const int lane = tid & 63;
    const int col  = lane & 31;
    const int g    = lane >> 5;

    {
        const float* xblk = x + (size_t)bid * 64 * 64;
        const int fi = tid * 4;
        fvec4 v = *(const fvec4*)(xblk + fi);
        const int r = fi >> 6, c = fi & 63;
        xs[r][c + 0] = v[0]; xs[r][c + 1] = v[1];
        xs[r][c + 2] = v[2]; xs[r][c + 3] = v[3];
    }
    const float SCQ = 0.25f * 1.44269504088896340736f; // 1/sqrt(16)*log2(e)
    {
        const int n = tid & 15, k = tid >> 4;          // Wq: 1 value/thread
        float wv = Wq[tid] * SCQ;
        unsigned short h = f2bf(wv);
        Wh[n][k] = h;
        Wl[n][k] = f2bf(wv - __uint_as_float((unsigned)h << 16));
    }
    {
        const int n = tid & 15, k = tid >> 4;          // Wk: 1 value/thread
        float wv = Wk[tid];
        unsigned short h = f2bf(wv);
        Wh[16 + n][k] = h;
        Wl[16 + n][k] = f2bf(wv - __uint_as_float((unsigned)h << 16));
    }
    #pragma unroll
    for (int j = 0; j < 4; ++j) {                      // Wv: 4 values/thread
        const int idx = tid + 1024 * j;
        const int n = idx & 63, k = idx >> 6;
        float wv = Wv[idx];
        unsigned short h = f2bf(wv);
        Wh[32 + n][k] = h;
        Wl[32 + n][k] = f2bf(wv - __uint_as_float((unsigned)h << 16));
    }
    __syncthreads();

    if (w < 6) {
        const int nt = w >> 1;            // 0: q/k, 1: v lo, 2: v hi
        const int rh = w & 1;             // which 32-row half
        const int row0 = bid * 64 + rh * 32;
        const int lrow = rh * 32 + col;

        s16x8 xh[4], xl[4];
        #pragma unroll
        for (int kc = 0; kc < 4; ++kc) {
            const float* xp = &xs[lrow][kc * 16 + 8 * g];
            float2 a0 = *(const float2*)(xp + 0);
            float2 a1 = *(const float2*)(xp + 2);
            float2 a2 = *(const float2*)(xp + 4);
            float2 a3 = *(const float2*)(xp + 6);
            I4S8 uh, ul;
            uh.i[0] = cvt_pk_bf16(a0.x, a0.y);
            uh.i[1] = cvt_pk_bf16(a1.x, a1.y);
            uh.i[2] = cvt_pk_bf16(a2.x, a2.y);
            uh.i[3] = cvt_pk_bf16(a3.x, a3.y);
            ul.i[0] = cvt_pk_bf16(a0.x - __uint_as_float((unsigned)uh.i[0] << 16),
                                  a0.y - __uint_as_float((unsigned)uh.i[0] & 0xffff0000u));
            ul.i[1] = cvt_pk_bf16(a1.x - __uint_as_float((unsigned)uh.i[1] << 16),
                                  a1.y - __uint_as_float((unsigned)uh.i[1] & 0xffff0000u));
            ul.i[2] = cvt_pk_bf16(a2.x - __uint_as_float((unsigned)uh.i[2] << 16),
                                  a2.y - __uint_as_float((unsigned)uh.i[2] & 0xffff0000u));
            ul.i[3] = cvt_pk_bf16(a3.x - __uint_as_float((unsigned)uh.i[3] << 16),
                                  a3.y - __uint_as_float((unsigned)uh.i[3] & 0xffff0000u));
            xh[kc] = uh.v; xl[kc] = ul.v;
        }

        f32x16 acc = (f32x16)0.0f;
        const int n = nt * 32 + col;
        #pragma unroll
        for (int kc = 0; kc < 4; ++kc) {
            const int off = kc * 16 + 8 * g;
            s16x8 bh = cat4(*(const s16x4*)&Wh[n][off], *(const s16x4*)&Wh[n][off + 4]);
            s16x8 bl = cat4(*(const s16x4*)&Wl[n][off], *(const s16x4*)&Wl[n][off + 4]);
            acc = __builtin_amdgcn_mfma_f32_32x32x16_bf16(xh[kc], bh, acc, 0, 0, 0);
            acc = __builtin_amdgcn_mfma_f32_32x32x16_bf16(xl[kc], bh, acc, 0, 0, 0);
            acc = __builtin_amdgcn_mfma_f32_32x32x16_bf16(xh[kc], bl, acc, 0, 0, 0);
        }

        if (nt == 0) {
            unsigned short* dst = (col < 16) ? (qb + col) : (kb + (col - 16));
            #pragma unroll
            for (int rr = 0; rr < 16; ++rr) {
                const int grow = row0 + (rr & 3) + 8 * (rr >> 2) + 4 * g;
                dst[(size_t)grow * 16] = f2bf(acc[rr]);
            }
        } else {
            const int mt = nt - 1;
            unsigned short* const vtile = vf + (size_t)bid * 4096;
            #pragma unroll
            for (int ci = 0; ci < 2; ++ci) {
                I4S8 pk;
                pk.i[0] = cvt_pk_bf16(acc[8*ci + 0], acc[8*ci + 1]);
                pk.i[1] = cvt_pk_bf16(acc[8*ci + 2], acc[8*ci + 3]);
                pk.i[2] = cvt_pk_bf16(acc[8*ci + 4], acc[8*ci + 5]);
                pk.i[3] = cvt_pk_bf16(acc[8*ci + 6], acc[8*ci + 7]);
                const int c = 2 * rh + ci;
                *(s16x8*)(vtile + ((c * 2 + mt) * 64 + lane) * 8) = pk.v;
            }
        }
    }
}

// ---------------------------------------------------------------------------
// One 32-key tile, register-dieted. DIAG: triangular mask.
// Loads staggered: kf+va00/va01 up front; va10/va11 issued after the QK MFMA
// (~120cy before first use). Denominator via 4 VALU chains (no osum AGPRs).
// ---------------------------------------------------------------------------
template<bool DIAG>
static __device__ __forceinline__ void do_tile32(
    const unsigned short* kp, const unsigned short* vt, const int lane,
    const s16x8 qf, const int col, const int g,
    f32x16& o0, f32x16& o1, float& lsum)
{
    s16x8 kf   = *(const s16x8*)(kp);
    s16x8 va00 = *(const s16x8*)(vt + (0 * 64 + lane) * 8);
    s16x8 va01 = *(const s16x8*)(vt + (1 * 64 + lane) * 8);

    f32x16 s = __builtin_amdgcn_mfma_f32_32x32x16_bf16(kf, qf, (f32x16)0.0f, 0, 0, 0);

    s16x8 va10 = *(const s16x8*)(vt + (2 * 64 + lane) * 8);
    s16x8 va11 = *(const s16x8*)(vt + (3 * 64 + lane) * 8);

    float psA = 0.f, psB = 0.f, psC = 0.f, psD = 0.f;
    #pragma unroll
    for (int rr = 0; rr < 16; ++rr) {
        float ev = __builtin_amdgcn_exp2f(s[rr]);
        if (DIAG) {
            const int drow = (rr & 3) + 8 * (rr >> 2) + 4 * g;
            ev = (drow <= col) ? ev : 0.f;
        }
        s[rr] = ev;
        if ((rr & 3) == 0) psA += ev; else if ((rr & 3) == 1) psB += ev;
        else if ((rr & 3) == 2) psC += ev; else psD += ev;
    }
    lsum += (psA + psB) + (psC + psD);

    I4S8 pa, pb;
    pa.i[0] = cvt_pk_bf16(s[0],  s[1]);
    pa.i[1] = cvt_pk_bf16(s[2],  s[3]);
    pa.i[2] = cvt_pk_bf16(s[4],  s[5]);
    pa.i[3] = cvt_pk_bf16(s[6],  s[7]);
    pb.i[0] = cvt_pk_bf16(s[8],  s[9]);
    pb.i[1] = cvt_pk_bf16(s[10], s[11]);
    pb.i[2] = cvt_pk_bf16(s[12], s[13]);
    pb.i[3] = cvt_pk_bf16(s[14], s[15]);

    o0 = __builtin_amdgcn_mfma_f32_32x32x16_bf16(va00, pa.v, o0, 0, 0, 0);
    o1 = __builtin_amdgcn_mfma_f32_32x32x16_bf16(va01, pa.v, o1, 0, 0, 0);
    o0 = __builtin_amdgcn_mfma_f32_32x32x16_bf16(va10, pb.v, o0, 0, 0, 0);
    o1 = __builtin_amdgcn_mfma_f32_32x32x16_bf16(va11, pb.v, o1, 0, 0, 0);
}

// ---------------------------------------------------------------------------
// Flash attention. 1024 thr = 16 waves; grid (64, NBATCH). Block p does
// q-tiles p and 127-p: 129 32-key tiles. Wave w: t = w, w+16, ... with
// incremental pointers. Partials merged 16-way through packed-bf16 LDS.
// ---------------------------------------------------------------------------
__global__ __launch_bounds__(1024)
__attribute__((amdgpu_waves_per_eu(4, 4)))
void attn_kernel(
    const unsigned short* __restrict__ qb, const unsigned short* __restrict__ kb,
    const unsigned short* __restrict__ vf, float* __restrict__ out)
{
    __shared__ float pl[16][32];
    __shared__ int   pOi[1024 * 17];     // [dvp*32+q]*17 + w; packed bf16 pairs
    __shared__ float outS[32][66];       // store bounce (coalescing)

    const int tid  = threadIdx.x;
    const int w    = tid >> 6;
    const int lane = tid & 63;
    const int col  = lane & 31;
    const int g    = lane >> 5;
    const int b    = blockIdx.y;
    const int p    = blockIdx.x;

    const unsigned short* const kbase = kb + (size_t)b * TSEQ * 16 + (size_t)col * 16 + 8 * g;
    const unsigned short* const vbase = vf + (size_t)b * 64 * 4096
                                      + (size_t)(w >> 1) * 4096 + (w & 1) * 2048;

    for (int half = 0; half < 2; ++half) {
        const int i  = half ? (127 - p) : p;
        const int q0 = i * 32;

        const s16x8 qf = *(const s16x8*)(qb + ((size_t)(b * TSEQ) + q0 + col) * 16 + 8 * g);

        f32x16 o0 = (f32x16)0.0f, o1 = (f32x16)0.0f;
        float lsum = 0.f;

        // incremental tile pointers: t = w + 16k -> kp += 16*512, vt += 8*4096
        const unsigned short* kp = kbase + (size_t)w * 512;
        const unsigned short* vt = vbase;
        int t = w;
        for (; t < i; t += 16) {             // full 32-key tiles
            do_tile32<false>(kp, vt, lane, qf, col, g, o0, o1, lsum);
            kp += 8192; vt += 32768;
        }
        if (t == i) {                        // this wave owns the diagonal tile
            do_tile32<true>(kp, vt, lane, qf, col, g, o0, o1, lsum);
        }
        lsum += __shfl_xor(lsum, 32);

        // -- write partials: lsum f32; O as packed bf16 dv-pairs (d0 even)
        if (g == 0) pl[w][col] = lsum;
        #pragma unroll
        for (int mt = 0; mt < 2; ++mt) {
            const f32x16 oa = mt ? o1 : o0;
            #pragma unroll
            for (int j = 0; j < 8; ++j) {
                const int rr = 2 * j;
                const int d0 = mt * 32 + (rr & 3) + 8 * (rr >> 2) + 4 * g;
                pOi[((d0 >> 1) * 32 + col) * 17 + w] = cvt_pk_bf16(oa[rr], oa[rr + 1]);
            }
        }
        __syncthreads();

        // -- one-pass 16-way merge: thread (q = tid&31, dvp = tid>>5)
        {
            const int q   = tid & 31;
            const int dvp = tid >> 5;        // dv pair index 0..31
            float L = 0.f;
            #pragma unroll
            for (int ww = 0; ww < 16; ++ww) L += pl[ww][q];
            const float inv = 1.0f / L;
            const int* prow = &pOi[(dvp * 32 + q) * 17];
            float sA = 0.f, sB = 0.f;
            #pragma unroll
            for (int c = 0; c < 16; ++c) {
                const int v = prow[c];
                sA += __uint_as_float((unsigned)v << 16);
                sB += __uint_as_float((unsigned)v & 0xffff0000u);
            }
            outS[q][2 * dvp + 0] = sA * inv;
            outS[q][2 * dvp + 1] = sB * inv;
        }
        __syncthreads();

        // -- coalesced store: thread (q2 = tid>>5, dvq = (tid&31)*2)
        {
            const int q2  = tid >> 5;
            const int dvq = (tid & 31) * 2;
            float2 v2 = *(const float2*)&outS[q2][dvq];
            *(float2*)(out + ((size_t)(b * TSEQ) + q0 + q2) * 64 + dvq) = v2;
        }
        // pOi reuse in next half is safe: reads completed before the barrier.
    }
}

// ---------------------------------------------------------------------------
extern "C" void kernel_launch(void* const* d_in, const int* in_sizes, int n_in,
                              void* d_out, int out_size, void* d_ws, size_t ws_size,
                              hipStream_t stream) {
    const float* x  = (const float*)d_in[0];
    const float* Wq = (const float*)d_in[1];
    const float* Wk = (const float*)d_in[2];
    const float* Wv = (const float*)d_in[3];

    // workspace: q (512KiB) | k (512KiB) | v-fragments (2MiB) = 3 MiB
    unsigned short* qb = (unsigned short*)d_ws;
    unsigned short* kb = qb + (size_t)NBATCH * TSEQ * 16;
    unsigned short* vf = kb + (size_t)NBATCH * TSEQ * 16;
    float* out = (float*)d_out;

    proj_kernel<<<dim3((NBATCH * TSEQ) / 64), 1024, 0, stream>>>(x, Wq, Wk, Wv, qb, kb, vf);
    attn_kernel<<<dim3(64, NBATCH), 1024, 0, stream>>>(qb, kb, vf, out);
}